// Round 5
// baseline (998.801 us; speedup 1.0000x reference)
//
#include <hip/hip_runtime.h>

typedef __bf16 bf16;
typedef __bf16 bf16x4 __attribute__((ext_vector_type(4)));
typedef __bf16 bf16x8 __attribute__((ext_vector_type(8)));
typedef float  f32x4  __attribute__((ext_vector_type(4)));
typedef unsigned int u32x4 __attribute__((ext_vector_type(4)));

#define MFMA16(a, b, c) __builtin_amdgcn_mfma_f32_16x16x32_bf16((a), (b), (c), 0, 0, 0)

constexpr int N_NODES = 50000;
constexpr int N_EDGES = 800000;
constexpr int D = 64;

// ---------------- fast-path workspace layout (~112.7 MB, proven available) ----
constexpr size_t OFF_FBUF   = 0;                       // bf16[N_NODES*D]
constexpr size_t OFF_H2     = 6400000;                 // bf16[N_EDGES*D]
constexpr size_t OFF_IPOS   = 108800000;               // int[N_EDGES]
constexpr size_t OFF_ROWPTR = 112000000;               // int[N_NODES+1]
constexpr size_t OFF_CURSOR = 112200064;               // int[N_NODES]
constexpr size_t OFF_COUNTS = 112400064;               // int[N_NODES]
constexpr size_t OFF_WBF    = 112600064;               // bf16[28672]
constexpr size_t OFF_FLAGS  = 112657408;               // int[2]
constexpr size_t WS_FAST_NEED = 112700000;

// ---------------- slow-path fallback layout --------------
constexpr size_t S_SBUF  = 0;
constexpr size_t S_FLAGS = 12800000;

constexpr int XS_STRIDE = 200;
constexpr int HS_STRIDE = 72;
constexpr int X2_STRIDE = 136;
constexpr int SA_STRIDE = 68;    // f32 sacc stride

// ---------------------------------------------------------------------------
// Per-block local dtype detection (uniform, ~100 broadcast loads).
// farr: any float-family array (feat or efeat). F32=1 -> f32; I64=1 -> int64.
// ---------------------------------------------------------------------------
__device__ inline void detect_local(const void* farr, const void* eidx,
                                    int& F32, int& I64) {
    const unsigned short* h = (const unsigned short*)farr;
    int c = 0;
    #pragma unroll
    for (int j = 0; j < 64; ++j) {
        const int e8 = (h[j * 2] >> 7) & 0xFF;
        c += (e8 >= 97 && e8 <= 157) ? 1 : 0;
    }
    F32 = (c < 48) ? 1 : 0;
    const int* ei = (const int*)eidx;
    int nz = 0;
    #pragma unroll
    for (int j = 0; j < 32; ++j) nz += (ei[j * 2 + 1] != 0) ? 1 : 0;
    I64 = (nz == 0) ? 1 : 0;
}

__device__ inline bf16x8 ld8(const void* base, size_t off, int f32f) {
    if (f32f) {
        const float* p = (const float*)base + off;
        const float4 a = *(const float4*)p;
        const float4 b = *(const float4*)(p + 4);
        bf16x8 r;
        r[0] = (bf16)a.x; r[1] = (bf16)a.y; r[2] = (bf16)a.z; r[3] = (bf16)a.w;
        r[4] = (bf16)b.x; r[5] = (bf16)b.y; r[6] = (bf16)b.z; r[7] = (bf16)b.w;
        return r;
    }
    return *(const bf16x8*)((const bf16*)base + off);
}

__device__ inline float ldf(const void* base, int i, int f32f) {
    return f32f ? ((const float*)base)[i] : (float)((const bf16*)base)[i];
}

__device__ inline int gidx(const void* e, size_t i, int i64f) {
    return i64f ? (int)((const long long*)e)[i] : ((const int*)e)[i];
}

// ---------------------------------------------------------------------------
// K1: merged prep: feat->bf16 conversion + src histogram (+ block0: weights->bf16,
// flags for later kernels). Grid 3125 x 256.
// ---------------------------------------------------------------------------
__global__ __launch_bounds__(256) void prep_kernel(
    const void* __restrict__ feat, const void* __restrict__ eidx,
    const void* __restrict__ W1, const void* __restrict__ W2,
    const void* __restrict__ W3, const void* __restrict__ W4,
    bf16* __restrict__ fbuf, int* __restrict__ counts,
    bf16* __restrict__ wbf, int* __restrict__ flags)
{
    int F32, I64;
    detect_local(feat, eidx, F32, I64);
    const int t = threadIdx.x;
    const int b = blockIdx.x;

    if (b == 0) {
        if (t == 0) { flags[0] = F32; flags[1] = I64; }
        for (int i = t; i < 28672; i += 256) {
            const void* src; int off;
            if (i < 12288)      { src = W1; off = i; }
            else if (i < 16384) { src = W2; off = i - 12288; }
            else if (i < 24576) { src = W3; off = i - 16384; }
            else                { src = W4; off = i - 24576; }
            wbf[i] = F32 ? (bf16)((const float*)src)[off] : ((const bf16*)src)[off];
        }
    }

    // feat conversion: 4 elems/thread
    const int i = b * 1024 + t * 4;
    if (F32) {
        const float4 v = *(const float4*)((const float*)feat + i);
        bf16x4 r; r[0] = (bf16)v.x; r[1] = (bf16)v.y; r[2] = (bf16)v.z; r[3] = (bf16)v.w;
        *(bf16x4*)(fbuf + i) = r;
    } else {
        *(bf16x4*)(fbuf + i) = *(const bf16x4*)((const bf16*)feat + i);
    }

    // histogram: 1 edge/thread
    const int e = b * 256 + t;
    atomicAdd(&counts[gidx(eidx, e, I64)], 1);
}

// ---------------------------------------------------------------------------
// K2: scan (single block)
// ---------------------------------------------------------------------------
__global__ void scan_kernel(const int* __restrict__ counts, int* __restrict__ rowptr,
                            int* __restrict__ cursor)
{
    __shared__ int part[256];
    const int t = threadIdx.x;
    const int base = t * 196;
    int s = 0;
    for (int i = 0; i < 196; ++i) {
        const int idx = base + i;
        if (idx < N_NODES) s += counts[idx];
    }
    part[t] = s;
    __syncthreads();
    if (t == 0) {
        int acc = 0;
        for (int i = 0; i < 256; ++i) { const int v = part[i]; part[i] = acc; acc += v; }
        rowptr[N_NODES] = acc;
    }
    __syncthreads();
    int acc = part[t];
    for (int i = 0; i < 196; ++i) {
        const int idx = base + i;
        if (idx < N_NODES) {
            rowptr[idx] = acc;
            cursor[idx] = acc;
            acc += counts[idx];
        }
    }
}

// ---------------------------------------------------------------------------
// K3: fill — CSR slot per edge
// ---------------------------------------------------------------------------
__global__ __launch_bounds__(256) void fill_kernel(
    const void* __restrict__ eidx, int* __restrict__ cursor,
    int* __restrict__ ipos)
{
    const int* ei = (const int*)eidx;
    int nz = 0;
    #pragma unroll
    for (int j = 0; j < 32; ++j) nz += (ei[j * 2 + 1] != 0) ? 1 : 0;
    const int I64 = (nz == 0) ? 1 : 0;
    const int e = blockIdx.x * 256 + threadIdx.x;
    const int src = gidx(eidx, (size_t)e, I64);
    ipos[e] = atomicAdd(&cursor[src], 1);
}

// ---------------------------------------------------------------------------
// K4: edge kernel. Wave = 64 edges (4 groups of 16), barrier-free.
// All W1/W2 B-fragments register-resident (loaded once per wave).
// A-fragments direct from global (fbuf gathers cached; efeat nontemporal).
// h2 rows -> h2ws[ipos[e]] via nontemporal 16B stores.
// ---------------------------------------------------------------------------
__global__ __launch_bounds__(256) void edge_fast(
    const bf16* __restrict__ fbuf, const void* __restrict__ eidx,
    const void* __restrict__ efeat,
    const bf16* __restrict__ wbf, const void* __restrict__ b1, const void* __restrict__ b2,
    const int* __restrict__ ipos, bf16* __restrict__ h2ws)
{
    __shared__ bf16 hs[4][16 * 72];
    __shared__ bf16 os[4][16 * 72];

    int F32, I64;
    detect_local(efeat, eidx, F32, I64);

    const int t    = threadIdx.x;
    const int wave = t >> 6;
    const int lane = t & 63;
    const int lrow = lane & 15;
    const int quad = lane >> 4;
    const int e0w  = blockIdx.x * 256 + wave * 64;   // wave's 64 edges

    const bf16* W1b = wbf;            // [64][192]
    const bf16* W2b = wbf + 12288;    // [64][64]

    // --- register-resident B fragments (shared across all 4 groups) ---
    bf16x8 B1[6][4];
    #pragma unroll
    for (int k = 0; k < 6; ++k)
        #pragma unroll
        for (int n = 0; n < 4; ++n)
            B1[k][n] = *(const bf16x8*)&W1b[(n * 16 + lrow) * 192 + k * 32 + quad * 8];
    bf16x8 B2[2][4];
    #pragma unroll
    for (int k = 0; k < 2; ++k)
        #pragma unroll
        for (int n = 0; n < 4; ++n)
            B2[k][n] = *(const bf16x8*)&W2b[(n * 16 + lrow) * D + k * 32 + quad * 8];
    float bb1[4], bb2[4];
    #pragma unroll
    for (int n = 0; n < 4; ++n) {
        bb1[n] = ldf(b1, n * 16 + lrow, F32);
        bb2[n] = ldf(b2, n * 16 + lrow, F32);
    }

    // --- prefetch all indices up front ---
    int srcs[4], dsts[4], ips[4];
    #pragma unroll
    for (int g = 0; g < 4; ++g) {
        const int eA = e0w + g * 16 + lrow;
        srcs[g] = gidx(eidx, (size_t)eA, I64);
        dsts[g] = gidx(eidx, (size_t)N_EDGES + eA, I64);
        ips[g]  = ipos[e0w + g * 16 + (lane >> 2)];
    }

    #pragma unroll
    for (int g = 0; g < 4; ++g) {
        const int eA = e0w + g * 16 + lrow;
        const int po0 = quad * 8, po1 = 32 + quad * 8;

        // A fragments: [fbuf[src] | efeat[e] | fbuf[dst]]
        bf16x8 A[6];
        A[0] = *(const bf16x8*)&fbuf[(size_t)srcs[g] * D + po0];
        A[1] = *(const bf16x8*)&fbuf[(size_t)srcs[g] * D + po1];
        if (F32) {
            const float* ef = (const float*)efeat + (size_t)eA * D;
            const f32x4 v0 = __builtin_nontemporal_load((const f32x4*)(ef + po0));
            const f32x4 v1 = __builtin_nontemporal_load((const f32x4*)(ef + po0 + 4));
            const f32x4 v2 = __builtin_nontemporal_load((const f32x4*)(ef + po1));
            const f32x4 v3 = __builtin_nontemporal_load((const f32x4*)(ef + po1 + 4));
            #pragma unroll
            for (int i = 0; i < 4; ++i) {
                A[2][i] = (bf16)v0[i]; A[2][4 + i] = (bf16)v1[i];
                A[3][i] = (bf16)v2[i]; A[3][4 + i] = (bf16)v3[i];
            }
        } else {
            const bf16* ef = (const bf16*)efeat + (size_t)eA * D;
            u32x4 u0 = __builtin_nontemporal_load((const u32x4*)(ef + po0));
            u32x4 u1 = __builtin_nontemporal_load((const u32x4*)(ef + po1));
            A[2] = *(bf16x8*)&u0;
            A[3] = *(bf16x8*)&u1;
        }
        A[4] = *(const bf16x8*)&fbuf[(size_t)dsts[g] * D + po0];
        A[5] = *(const bf16x8*)&fbuf[(size_t)dsts[g] * D + po1];

        // GEMM1: K=192
        f32x4 acc[4] = {{0,0,0,0},{0,0,0,0},{0,0,0,0},{0,0,0,0}};
        #pragma unroll
        for (int k = 0; k < 6; ++k)
            #pragma unroll
            for (int n = 0; n < 4; ++n)
                acc[n] = MFMA16(A[k], B1[k][n], acc[n]);

        // ReLU+b1: C-layout -> wave-private LDS (A-layout for GEMM2)
        #pragma unroll
        for (int n = 0; n < 4; ++n) {
            const int col = n * 16 + lrow;
            #pragma unroll
            for (int r = 0; r < 4; ++r) {
                float v = acc[n][r] + bb1[n];
                v = v > 0.f ? v : 0.f;
                hs[wave][(quad * 4 + r) * 72 + col] = (bf16)v;
            }
        }

        // GEMM2: K=64
        f32x4 acc2[4] = {{0,0,0,0},{0,0,0,0},{0,0,0,0},{0,0,0,0}};
        #pragma unroll
        for (int k = 0; k < 2; ++k) {
            const bf16x8 a = *(const bf16x8*)&hs[wave][lrow * 72 + k * 32 + quad * 8];
            #pragma unroll
            for (int n = 0; n < 4; ++n)
                acc2[n] = MFMA16(a, B2[k][n], acc2[n]);
        }

        // h2 + b2 -> os, then coalesced nontemporal 32B/lane store
        #pragma unroll
        for (int n = 0; n < 4; ++n) {
            const int col = n * 16 + lrow;
            #pragma unroll
            for (int r = 0; r < 4; ++r)
                os[wave][(quad * 4 + r) * 72 + col] = (bf16)(acc2[n][r] + bb2[n]);
        }

        const int row = lane >> 2;
        const int seg = lane & 3;
        const u32x4 v0 = *(const u32x4*)&os[wave][row * 72 + seg * 16];
        const u32x4 v1 = *(const u32x4*)&os[wave][row * 72 + seg * 16 + 8];
        bf16* dstp = &h2ws[(size_t)ips[g] * D + seg * 16];
        __builtin_nontemporal_store(v0, (u32x4*)dstp);
        __builtin_nontemporal_store(v1, (u32x4*)(dstp + 8));
    }
}

// ---------------------------------------------------------------------------
// K5: fused node kernel. Phase 1: coalesced CSR segment-sum into LDS f32
// (64-row chunks, binary-search row->node). Phase 2: node MLP.
// ---------------------------------------------------------------------------
__global__ __launch_bounds__(256) void node_fused(
    const bf16* __restrict__ fbuf, const bf16* __restrict__ h2ws,
    const int* __restrict__ rowptr,
    const bf16* __restrict__ wbf, const void* __restrict__ b3, const void* __restrict__ b4,
    void* __restrict__ out, const int* __restrict__ flags)
{
    __shared__ float sacc[64 * SA_STRIDE];
    __shared__ int   rp[65];
    __shared__ bf16  xs[64 * X2_STRIDE];
    __shared__ bf16  h3s[64 * HS_STRIDE];

    const int t  = threadIdx.x;
    const int r0 = blockIdx.x * 64;
    const int F32 = flags[0];

    for (int i = t; i < 64 * SA_STRIDE; i += 256) sacc[i] = 0.f;
    if (t < 65) {
        int node = r0 + t;
        if (node > N_NODES) node = N_NODES;
        rp[t] = rowptr[node];
    }
    __syncthreads();

    // Phase 1: segment sum (coalesced 64-row chunks)
    {
        const int jb = rp[0], je = rp[64];
        const int row4 = t >> 2;
        const int seg  = t & 3;
        for (int j0 = jb; j0 < je; j0 += 64) {
            const int j = j0 + row4;
            if (j < je) {
                const bf16* src = &h2ws[(size_t)j * D + seg * 16];
                u32x4 u0 = __builtin_nontemporal_load((const u32x4*)src);
                u32x4 u1 = __builtin_nontemporal_load((const u32x4*)(src + 8));
                const bf16x8 a0 = *(bf16x8*)&u0;
                const bf16x8 a1 = *(bf16x8*)&u1;
                // binary search: largest nd with rp[nd] <= j
                int lo = 0, hi = 64;
                #pragma unroll
                for (int s = 0; s < 6; ++s) {
                    const int mid = (lo + hi) >> 1;
                    if (j >= rp[mid]) lo = mid; else hi = mid;
                }
                float* dstp = &sacc[lo * SA_STRIDE + seg * 16];
                #pragma unroll
                for (int i = 0; i < 8; ++i) {
                    atomicAdd(&dstp[i],     (float)a0[i]);
                    atomicAdd(&dstp[8 + i], (float)a1[i]);
                }
            }
        }
    }
    __syncthreads();

    // Phase 2: stage [feat | feat+s] and run MLP
    for (int i = t; i < 64 * 8; i += 256) {
        const int r = i >> 3;
        const int c = i & 7;
        const int node = r0 + r;
        bf16x8 fv = {0,0,0,0,0,0,0,0};
        bf16x8 sv = {0,0,0,0,0,0,0,0};
        if (node < N_NODES) {
            fv = *(const bf16x8*)&fbuf[(size_t)node * D + c * 8];
            #pragma unroll
            for (int k = 0; k < 8; ++k)
                sv[k] = (bf16)((float)fv[k] + sacc[r * SA_STRIDE + c * 8 + k]);
        }
        *(bf16x8*)&xs[r * X2_STRIDE + c * 8]      = fv;
        *(bf16x8*)&xs[r * X2_STRIDE + 64 + c * 8] = sv;
    }
    __syncthreads();

    const int wave = t >> 6;
    const int lane = t & 63;
    const int m0   = wave * 16;
    const int lrow = lane & 15;
    const int quad = lane >> 4;
    const bf16* W3b = wbf + 16384;
    const bf16* W4b = wbf + 24576;

    f32x4 acc[4] = {{0,0,0,0},{0,0,0,0},{0,0,0,0},{0,0,0,0}};
    #pragma unroll
    for (int k = 0; k < 4; ++k) {
        const bf16x8 a = *(const bf16x8*)&xs[(m0 + lrow) * X2_STRIDE + k * 32 + quad * 8];
        #pragma unroll
        for (int n = 0; n < 4; ++n) {
            const bf16x8 b = *(const bf16x8*)&W3b[(n * 16 + lrow) * 128 + k * 32 + quad * 8];
            acc[n] = MFMA16(a, b, acc[n]);
        }
    }

    #pragma unroll
    for (int n = 0; n < 4; ++n) {
        const int col  = n * 16 + lrow;
        const float bb = ldf(b3, col, F32);
        #pragma unroll
        for (int r = 0; r < 4; ++r) {
            float v = acc[n][r] + bb;
            v = v > 0.f ? v : 0.f;
            h3s[(m0 + quad * 4 + r) * HS_STRIDE + col] = (bf16)v;
        }
    }

    f32x4 acc2[4] = {{0,0,0,0},{0,0,0,0},{0,0,0,0},{0,0,0,0}};
    #pragma unroll
    for (int k = 0; k < 2; ++k) {
        const bf16x8 a = *(const bf16x8*)&h3s[(m0 + lrow) * HS_STRIDE + k * 32 + quad * 8];
        #pragma unroll
        for (int n = 0; n < 4; ++n) {
            const bf16x8 b = *(const bf16x8*)&W4b[(n * 16 + lrow) * D + k * 32 + quad * 8];
            acc2[n] = MFMA16(a, b, acc2[n]);
        }
    }

    #pragma unroll
    for (int n = 0; n < 4; ++n) {
        const int col  = n * 16 + lrow;
        const float bb = ldf(b4, col, F32);
        #pragma unroll
        for (int r = 0; r < 4; ++r) {
            const int node = r0 + m0 + quad * 4 + r;
            if (node < N_NODES) {
                const float v = acc2[n][r] + bb;
                if (F32) ((float*)out)[(size_t)node * D + col] = v;
                else     ((bf16*)out)[(size_t)node * D + col] = (bf16)v;
            }
        }
    }
}

// ---------------------------------------------------------------------------
// SLOW fallback (R2-proven) — only if ws_size too small for the fast path.
// ---------------------------------------------------------------------------
__global__ void detect_kernel(const void* __restrict__ feat,
                              const void* __restrict__ eidx,
                              int* __restrict__ flags)
{
    int F32, I64;
    detect_local(feat, eidx, F32, I64);
    if (threadIdx.x == 0) { flags[0] = F32; flags[1] = I64; }
}

__global__ __launch_bounds__(256) void edge_slow(
    const void* __restrict__ feat, const void* __restrict__ eidx,
    const void* __restrict__ efeat,
    const void* __restrict__ W1, const void* __restrict__ b1,
    const void* __restrict__ W2, const void* __restrict__ b2,
    float* __restrict__ sbuf, const int* __restrict__ flags)
{
    __shared__ bf16 xs[64 * XS_STRIDE];
    __shared__ bf16 h1s[64 * HS_STRIDE];
    __shared__ int  srcs[64];
    __shared__ int  fl[2];

    const int t  = threadIdx.x;
    const int e0 = blockIdx.x * 64;

    if (t < 2) fl[t] = flags[t];
    __syncthreads();
    const int F32 = fl[0], I64 = fl[1];

    if (t < 64) srcs[t] = gidx(eidx, e0 + t, I64);

    for (int i = t; i < 64 * 24; i += 256) {
        const int e    = i / 24;
        const int c    = i - e * 24;
        const int part = c >> 3;
        const int cc   = c & 7;
        size_t off;
        const void* base;
        if (part == 0)      { base = feat;  off = (size_t)gidx(eidx, e0 + e, I64) * D + cc * 8; }
        else if (part == 1) { base = efeat; off = (size_t)(e0 + e) * D + cc * 8; }
        else                { base = feat;  off = (size_t)gidx(eidx, (size_t)N_EDGES + e0 + e, I64) * D + cc * 8; }
        *(bf16x8*)&xs[e * XS_STRIDE + part * 64 + cc * 8] = ld8(base, off, F32);
    }
    __syncthreads();

    const int wave = t >> 6;
    const int lane = t & 63;
    const int m0   = wave * 16;
    const int lrow = lane & 15;
    const int quad = lane >> 4;

    f32x4 acc[4] = {{0,0,0,0},{0,0,0,0},{0,0,0,0},{0,0,0,0}};
    #pragma unroll
    for (int k = 0; k < 6; ++k) {
        const bf16x8 a = *(const bf16x8*)&xs[(m0 + lrow) * XS_STRIDE + k * 32 + quad * 8];
        #pragma unroll
        for (int n = 0; n < 4; ++n) {
            const bf16x8 b = ld8(W1, (size_t)(n * 16 + lrow) * 192 + k * 32 + quad * 8, F32);
            acc[n] = MFMA16(a, b, acc[n]);
        }
    }

    #pragma unroll
    for (int n = 0; n < 4; ++n) {
        const int col  = n * 16 + lrow;
        const float bb = ldf(b1, col, F32);
        #pragma unroll
        for (int r = 0; r < 4; ++r) {
            float v = acc[n][r] + bb;
            v = v > 0.f ? v : 0.f;
            h1s[(m0 + quad * 4 + r) * HS_STRIDE + col] = (bf16)v;
        }
    }
    __syncthreads();

    f32x4 acc2[4] = {{0,0,0,0},{0,0,0,0},{0,0,0,0},{0,0,0,0}};
    #pragma unroll
    for (int k = 0; k < 2; ++k) {
        const bf16x8 a = *(const bf16x8*)&h1s[(m0 + lrow) * HS_STRIDE + k * 32 + quad * 8];
        #pragma unroll
        for (int n = 0; n < 4; ++n) {
            const bf16x8 b = ld8(W2, (size_t)(n * 16 + lrow) * D + k * 32 + quad * 8, F32);
            acc2[n] = MFMA16(a, b, acc2[n]);
        }
    }

    #pragma unroll
    for (int n = 0; n < 4; ++n) {
        const int col  = n * 16 + lrow;
        const float bb = ldf(b2, col, F32);
        #pragma unroll
        for (int r = 0; r < 4; ++r) {
            const int e = m0 + quad * 4 + r;
            atomicAdd(&sbuf[(size_t)srcs[e] * D + col], acc2[n][r] + bb);
        }
    }
}

__global__ __launch_bounds__(256) void node_slow(
    const void* __restrict__ feat, const float* __restrict__ sbuf,
    const void* __restrict__ W3, const void* __restrict__ b3,
    const void* __restrict__ W4, const void* __restrict__ b4,
    void* __restrict__ out, const int* __restrict__ flags)
{
    __shared__ bf16 xs[64 * X2_STRIDE];
    __shared__ bf16 h3s[64 * HS_STRIDE];
    __shared__ int fl[1];

    const int t  = threadIdx.x;
    const int r0 = blockIdx.x * 64;

    if (t == 0) fl[0] = flags[0];
    __syncthreads();
    const int F32 = fl[0];

    for (int i = t; i < 64 * 8; i += 256) {
        const int r    = i >> 3;
        const int c    = i & 7;
        const int node = r0 + r;
        bf16x8 fv = {0,0,0,0,0,0,0,0};
        bf16x8 sv = {0,0,0,0,0,0,0,0};
        if (node < N_NODES) {
            fv = ld8(feat, (size_t)node * D + c * 8, F32);
            const float4 sa = *(const float4*)&sbuf[(size_t)node * D + c * 8];
            const float4 sb = *(const float4*)&sbuf[(size_t)node * D + c * 8 + 4];
            sv[0] = (bf16)((float)fv[0] + sa.x);
            sv[1] = (bf16)((float)fv[1] + sa.y);
            sv[2] = (bf16)((float)fv[2] + sa.z);
            sv[3] = (bf16)((float)fv[3] + sa.w);
            sv[4] = (bf16)((float)fv[4] + sb.x);
            sv[5] = (bf16)((float)fv[5] + sb.y);
            sv[6] = (bf16)((float)fv[6] + sb.z);
            sv[7] = (bf16)((float)fv[7] + sb.w);
        }
        *(bf16x8*)&xs[r * X2_STRIDE + c * 8]      = fv;
        *(bf16x8*)&xs[r * X2_STRIDE + 64 + c * 8] = sv;
    }
    __syncthreads();

    const int wave = t >> 6;
    const int lane = t & 63;
    const int m0   = wave * 16;
    const int lrow = lane & 15;
    const int quad = lane >> 4;

    f32x4 acc[4] = {{0,0,0,0},{0,0,0,0},{0,0,0,0},{0,0,0,0}};
    #pragma unroll
    for (int k = 0; k < 4; ++k) {
        const bf16x8 a = *(const bf16x8*)&xs[(m0 + lrow) * X2_STRIDE + k * 32 + quad * 8];
        #pragma unroll
        for (int n = 0; n < 4; ++n) {
            const bf16x8 b = ld8(W3, (size_t)(n * 16 + lrow) * 128 + k * 32 + quad * 8, F32);
            acc[n] = MFMA16(a, b, acc[n]);
        }
    }

    #pragma unroll
    for (int n = 0; n < 4; ++n) {
        const int col  = n * 16 + lrow;
        const float bb = ldf(b3, col, F32);
        #pragma unroll
        for (int r = 0; r < 4; ++r) {
            float v = acc[n][r] + bb;
            v = v > 0.f ? v : 0.f;
            h3s[(m0 + quad * 4 + r) * HS_STRIDE + col] = (bf16)v;
        }
    }
    __syncthreads();

    f32x4 acc2[4] = {{0,0,0,0},{0,0,0,0},{0,0,0,0},{0,0,0,0}};
    #pragma unroll
    for (int k = 0; k < 2; ++k) {
        const bf16x8 a = *(const bf16x8*)&h3s[(m0 + lrow) * HS_STRIDE + k * 32 + quad * 8];
        #pragma unroll
        for (int n = 0; n < 4; ++n) {
            const bf16x8 b = ld8(W4, (size_t)(n * 16 + lrow) * D + k * 32 + quad * 8, F32);
            acc2[n] = MFMA16(a, b, acc2[n]);
        }
    }

    #pragma unroll
    for (int n = 0; n < 4; ++n) {
        const int col  = n * 16 + lrow;
        const float bb = ldf(b4, col, F32);
        #pragma unroll
        for (int r = 0; r < 4; ++r) {
            const int node = r0 + m0 + quad * 4 + r;
            if (node < N_NODES) {
                const float v = acc2[n][r] + bb;
                if (F32) ((float*)out)[(size_t)node * D + col] = v;
                else     ((bf16*)out)[(size_t)node * D + col] = (bf16)v;
            }
        }
    }
}

extern "C" void kernel_launch(void* const* d_in, const int* in_sizes, int n_in,
                              void* d_out, int out_size, void* d_ws, size_t ws_size,
                              hipStream_t stream) {
    const void* feat  = d_in[0];
    const void* eidx  = d_in[1];
    const void* efeat = d_in[2];
    const void* W1    = d_in[3];
    const void* b1    = d_in[4];
    const void* W2    = d_in[5];
    const void* b2    = d_in[6];
    const void* W3    = d_in[7];
    const void* b3    = d_in[8];
    const void* W4    = d_in[9];
    const void* b4    = d_in[10];

    char* ws = (char*)d_ws;

    if (ws_size >= WS_FAST_NEED) {
        bf16* fbuf   = (bf16*)(ws + OFF_FBUF);
        bf16* h2ws   = (bf16*)(ws + OFF_H2);
        int*  ipos   = (int*)(ws + OFF_IPOS);
        int*  rowptr = (int*)(ws + OFF_ROWPTR);
        int*  cursor = (int*)(ws + OFF_CURSOR);
        int*  counts = (int*)(ws + OFF_COUNTS);
        bf16* wbf    = (bf16*)(ws + OFF_WBF);
        int*  flags  = (int*)(ws + OFF_FLAGS);

        hipMemsetAsync(counts, 0, (size_t)N_NODES * sizeof(int), stream);
        prep_kernel<<<3125, 256, 0, stream>>>(feat, eidx, W1, W2, W3, W4,
                                              fbuf, counts, wbf, flags);
        scan_kernel<<<1, 256, 0, stream>>>(counts, rowptr, cursor);
        fill_kernel<<<N_EDGES / 256, 256, 0, stream>>>(eidx, cursor, ipos);
        edge_fast<<<N_EDGES / 256, 256, 0, stream>>>(fbuf, eidx, efeat, wbf, b1, b2,
                                                     ipos, h2ws);
        node_fused<<<(N_NODES + 63) / 64, 256, 0, stream>>>(fbuf, h2ws, rowptr,
                                                            wbf, b3, b4, d_out, flags);
    } else {
        float* sbuf  = (float*)(ws + S_SBUF);
        int*   flags = (int*)(ws + S_FLAGS);

        detect_kernel<<<1, 64, 0, stream>>>(feat, eidx, flags);
        hipMemsetAsync(sbuf, 0, (size_t)N_NODES * D * sizeof(float), stream);
        edge_slow<<<N_EDGES / 64, 256, 0, stream>>>(feat, eidx, efeat, W1, b1, W2, b2,
                                                    sbuf, flags);
        node_slow<<<(N_NODES + 63) / 64, 256, 0, stream>>>(feat, sbuf, W3, b3, W4, b4,
                                                           d_out, flags);
    }
}